// Round 12
// baseline (247.126 us; speedup 1.0000x reference)
//
#include <hip/hip_runtime.h>
#include <hip/hip_bf16.h>
#include <stdint.h>

#define BATCH   65536
#define UNITS   256
#define NCHUNK  8
#define ROWP    68                     // shorts per column in gate buffer (2-bank stride)
#define GSZ     (64 * ROWP)            // 4352 shorts per gate
#define SMEM_BYTES 34816               // max(A dbuf 16384, G 4*GSZ*2 = 34816)

using f32x16 = __attribute__((ext_vector_type(16))) float;
using bf16x8 = __attribute__((ext_vector_type(8))) short;

__device__ __forceinline__ short f2bf(float f) {
  union { float f; unsigned u; } v; v.f = f;
  unsigned r = v.u + 0x7FFFu + ((v.u >> 16) & 1u);   // RNE (prepass only)
  return (short)(r >> 16);
}
__device__ __forceinline__ float bf2f(short s) {
  union { float f; unsigned u; } v; v.u = ((unsigned)(unsigned short)s) << 16;
  return v.f;
}
__device__ __forceinline__ unsigned pk2(float a, float b) {   // v_cvt_pk_bf16_f32
  union { __hip_bfloat162 h; unsigned u; } cv;
  cv.h = __float22bfloat162_rn(make_float2(a, b));
  return cv.u;
}
__device__ __forceinline__ bf16x8 cvt8(float4 a, float4 b) {
  union { unsigned u[4]; bf16x8 v; } r;
  r.u[0] = pk2(a.x, a.y); r.u[1] = pk2(a.z, a.w);
  r.u[2] = pk2(b.x, b.y); r.u[3] = pk2(b.z, b.w);
  return r.v;
}

// fast activations: v_exp_f32 (2^x) + v_rcp_f32, 4-5 VALU each, saturate cleanly
#define LOG2E 1.4426950408889634f
__device__ __forceinline__ float fast_sigmoid(float x) {
  return __builtin_amdgcn_rcpf(1.f + __builtin_amdgcn_exp2f(x * -LOG2E));
}
__device__ __forceinline__ float fast_tanh(float x) {
  return 2.f * __builtin_amdgcn_rcpf(1.f + __builtin_amdgcn_exp2f(x * (-2.f * LOG2E))) - 1.f;
}

#define BAR() do { asm volatile("s_waitcnt lgkmcnt(0)" ::: "memory"); \
                   __builtin_amdgcn_s_barrier(); } while (0)

// ---- prepass: W_g fp32 [512][256] -> Wt bf16 tiled [g][nb][c][kg][n][k8]
__global__ void cvt_weights(const float* __restrict__ Wf, const float* __restrict__ Wi,
                            const float* __restrict__ Wc, const float* __restrict__ Wo,
                            short* __restrict__ Wt) {
  int idx = blockIdx.x * 256 + threadIdx.x;
  int g   = idx >> 17;
  int k   = (idx >> 8) & 511;
  int col = idx & 255;
  const float* W = (g == 0) ? Wf : (g == 1) ? Wi : (g == 2) ? Wc : Wo;
  float val = W[k * 256 + col];
  int nb = col >> 6, n = col & 63;
  int c = k >> 6, kg = (k >> 3) & 7, k8 = k & 7;
  int out = ((((g * 4 + nb) * 8 + c) * 8 + kg) * 64 + n) * 8 + k8;
  Wt[out] = f2bf(val);
}

// ---- fused LSTM cell: R11 structure + DIAGNOSTIC PASS-1 (exact no-op):
// the full K-loop (real B loads, ds_reads, MFMAs, barriers) runs once against
// a zeroed A buffer (acc += 0 exactly), then the real pipeline runs.
// Output is bit-identical to R11; the marginal dur isolates the K-loop cost.
__global__ __launch_bounds__(256, 3) void lstm_fused(
    const float* __restrict__ x, const float* __restrict__ hprev,
    const float* __restrict__ cprev, const short* __restrict__ Wt,
    const float* __restrict__ bfp, const float* __restrict__ bip,
    const float* __restrict__ bcp, const float* __restrict__ bop,
    float* __restrict__ hout, float* __restrict__ cout)
{
  extern __shared__ __align__(16) char smem[];
  const int tid  = threadIdx.x;
  const int g    = tid >> 6;           // wave = gate
  const int lane = tid & 63;
  const int la   = lane & 31;
  const int hh   = lane >> 5;

  int bid = blockIdx.x;
  int wg  = (bid & 7) * 512 + (bid >> 3);      // XCD-bijective swizzle
  const int m0 = (wg >> 2) * 64;
  const int nb = wg & 3;
  const int n0 = nb * 64;

  const short* Bbase = Wt + ((size_t)(g * 4 + nb)) * 32768 + hh * 512 + la * 8;

  f32x16 acc[2][2] = {};
  bf16x8 breg[8];
  float4 vA[2][4];

  const int arow  = tid >> 2;
  const int q     = tid & 3;
  const int slotW = (arow ^ (q << 2)) & 63;

  auto ldA = [&](int c, float4* v) {
    const float* base = (c < 4) ? x : hprev;
    const float* rowp = base + (size_t)(m0 + arow) * 256 + (c & 3) * 64;
    v[0] = *(const float4*)(rowp + q * 8);
    v[1] = *(const float4*)(rowp + q * 8 + 4);
    v[2] = *(const float4*)(rowp + (q + 4) * 8);
    v[3] = *(const float4*)(rowp + (q + 4) * 8 + 4);
  };
  auto wrA = [&](int buf, const float4* v) {
    char* Ab = smem + buf * 8192;
    *(bf16x8*)(Ab + q * 1024 + slotW * 16)       = cvt8(v[0], v[1]);
    *(bf16x8*)(Ab + (q + 4) * 1024 + slotW * 16) = cvt8(v[2], v[3]);
  };
  auto loadB = [&](int c, int ks) {
    const short* Bc = Bbase + (size_t)c * 4096 + ks * 1024;
    breg[2 * ks]     = *(const bf16x8*)(Bc);
    breg[2 * ks + 1] = *(const bf16x8*)(Bc + 256);
  };

  // epilogue-combine indices (cprev loads issued early, before the K loop)
  const int ccol = tid & 63;
  const int rg   = tid >> 6;
  const size_t gbase = (size_t)(m0 + rg * 16) * 256 + n0 + ccol;

  // ================= PASS 1 (diagnostic, exact no-op on acc) =================
  {
    const bf16x8 z = {0, 0, 0, 0, 0, 0, 0, 0};
    *(bf16x8*)(smem + tid * 32)      = z;          // zero buf0: 256 thr x 32 B
    *(bf16x8*)(smem + tid * 32 + 16) = z;
  }
  BAR();
#pragma unroll
  for (int ks = 0; ks < 4; ++ks) loadB(0, ks);     // real B(0) from L2
#pragma unroll
  for (int c = 0; c < NCHUNK; ++c) {
    const short* Bn = Bbase + (size_t)((c + 1) & 7) * 4096;
#pragma unroll
    for (int ks = 0; ks < 4; ++ks) {
      const int kg   = 2 * ks + hh;
      const int slot = la ^ ((kg & 3) << 2);
      const int off  = kg * 1024 + slot * 16;
      bf16x8 a0 = *(const bf16x8*)(smem + off);          // zero A
      bf16x8 a1 = *(const bf16x8*)(smem + off + 512);
      acc[0][0] = __builtin_amdgcn_mfma_f32_32x32x16_bf16(a0, breg[2*ks],   acc[0][0], 0, 0, 0);
      acc[0][1] = __builtin_amdgcn_mfma_f32_32x32x16_bf16(a0, breg[2*ks+1], acc[0][1], 0, 0, 0);
      acc[1][0] = __builtin_amdgcn_mfma_f32_32x32x16_bf16(a1, breg[2*ks],   acc[1][0], 0, 0, 0);
      acc[1][1] = __builtin_amdgcn_mfma_f32_32x32x16_bf16(a1, breg[2*ks+1], acc[1][1], 0, 0, 0);
      breg[2*ks]     = *(const bf16x8*)(Bn + ks * 1024);        // real prefetch
      breg[2*ks + 1] = *(const bf16x8*)(Bn + ks * 1024 + 256);
    }
    BAR();
  }
  // ================= PASS 2: the real R11 pipeline =================

  // ---- prologue ----
  ldA(0, vA[0]);                       // A(0) in flight
  ldA(1, vA[1]);                       // A(1) in flight
  wrA(0, vA[0]);                       // waits A(0) only (oldest)
#pragma unroll
  for (int ks = 0; ks < 4; ++ks) loadB(0, ks);   // B(0): after the A(0) wait
  float cp[16];
#pragma unroll
  for (int j = 0; j < 16; ++j) cp[j] = cprev[gbase + (size_t)j * 256];
  ldA(2, vA[0]);                       // A(2): newest in FIFO
  BAR();

  // ---- fully unrolled pipelined K loop (static vA indices — no scratch) ----
  int buf = 0;
#pragma unroll
  for (int c = 0; c < NCHUNK; ++c) {
    if (c + 1 < NCHUNK) wrA(buf ^ 1, vA[(c + 1) & 1]);  // A(c+1): ≥2 iters old
    if (c + 3 < NCHUNK) ldA(c + 3, vA[(c + 3) & 1]);    // refill freed buffer
    const char*  Ab = smem + buf * 8192;
    const short* Bn = Bbase + (size_t)((c + 1) & 7) * 4096;
#pragma unroll
    for (int ks = 0; ks < 4; ++ks) {
      const int kg   = 2 * ks + hh;
      const int slot = la ^ ((kg & 3) << 2);
      const int off  = kg * 1024 + slot * 16;
      bf16x8 a0 = *(const bf16x8*)(Ab + off);
      bf16x8 a1 = *(const bf16x8*)(Ab + off + 512);
      acc[0][0] = __builtin_amdgcn_mfma_f32_32x32x16_bf16(a0, breg[2*ks],   acc[0][0], 0, 0, 0);
      acc[0][1] = __builtin_amdgcn_mfma_f32_32x32x16_bf16(a0, breg[2*ks+1], acc[0][1], 0, 0, 0);
      acc[1][0] = __builtin_amdgcn_mfma_f32_32x32x16_bf16(a1, breg[2*ks],   acc[1][0], 0, 0, 0);
      acc[1][1] = __builtin_amdgcn_mfma_f32_32x32x16_bf16(a1, breg[2*ks+1], acc[1][1], 0, 0, 0);
      breg[2*ks]     = *(const bf16x8*)(Bn + ks * 1024);        // prefetch c+1
      breg[2*ks + 1] = *(const bf16x8*)(Bn + ks * 1024 + 256);
    }
    BAR();                             // lgkmcnt(0)+s_barrier; vmcnt stays live
    buf ^= 1;
  }

  // ---- epilogue: bias+activation -> transposed gate buffer [g][col][row]
  const float* bptr = (g == 0) ? bfp : (g == 1) ? bip : (g == 2) ? bcp : bop;
  const float bias0 = bptr[n0 + la];
  const float bias1 = bptr[n0 + 32 + la];
  short* G = (short*)smem;
#pragma unroll
  for (int mi = 0; mi < 2; ++mi)
#pragma unroll
    for (int ni = 0; ni < 2; ++ni) {
      const float bias = ni ? bias1 : bias0;
      const int   col  = la + ni * 32;
#pragma unroll
      for (int rq = 0; rq < 4; ++rq) {
        const int row0 = rq * 8 + 4 * hh + mi * 32;
        float t[4];
#pragma unroll
        for (int e = 0; e < 4; ++e) {
          float vv = acc[mi][ni][rq * 4 + e] + bias;
          t[e] = (g == 2) ? fast_tanh(vv) : fast_sigmoid(vv);
        }
        uint2 u; u.x = pk2(t[0], t[1]); u.y = pk2(t[2], t[3]);
        *(uint2*)(G + g * GSZ + col * ROWP + row0) = u;
      }
    }
  BAR();

  // ---- combine + store: thread -> col = tid&63, rows rg*16..+15 ----
  {
    const short* Gp = G + ccol * ROWP + rg * 16;
    bf16x8 gf[4][2];
#pragma unroll
    for (int gg = 0; gg < 4; ++gg) {
      gf[gg][0] = *(const bf16x8*)(Gp + gg * GSZ);
      gf[gg][1] = *(const bf16x8*)(Gp + gg * GSZ + 8);
    }
#pragma unroll
    for (int j = 0; j < 16; ++j) {
      float fg = bf2f(gf[0][j >> 3][j & 7]);
      float ig = bf2f(gf[1][j >> 3][j & 7]);
      float cg = bf2f(gf[2][j >> 3][j & 7]);
      float og = bf2f(gf[3][j >> 3][j & 7]);
      float cnew = fg * cp[j] + ig * cg;
      float hnew = og * fast_tanh(cnew);
      hout[gbase + (size_t)j * 256] = hnew;
      cout[gbase + (size_t)j * 256] = cnew;
    }
  }
}

extern "C" void kernel_launch(void* const* d_in, const int* in_sizes, int n_in,
                              void* d_out, int out_size, void* d_ws, size_t ws_size,
                              hipStream_t stream) {
  const float* x     = (const float*)d_in[0];
  const float* hprev = (const float*)d_in[1];
  const float* cprev = (const float*)d_in[2];
  const float* Wf    = (const float*)d_in[3];
  const float* Wi    = (const float*)d_in[4];
  const float* Wc    = (const float*)d_in[5];
  const float* Wo    = (const float*)d_in[6];
  const float* bfp   = (const float*)d_in[7];
  const float* bip   = (const float*)d_in[8];
  const float* bcp   = (const float*)d_in[9];
  const float* bop   = (const float*)d_in[10];
  float* out = (float*)d_out;
  short* Wt  = (short*)d_ws;     // 1 MB scratch

  cvt_weights<<<2048, 256, 0, stream>>>(Wf, Wi, Wc, Wo, Wt);

  lstm_fused<<<dim3(4096), dim3(256), SMEM_BYTES, stream>>>(
      x, hprev, cprev, Wt, bfp, bip, bcp, bop,
      out, out + (size_t)BATCH * UNITS);
}

// Round 13
// 143.543 us; speedup vs baseline: 1.7216x; 1.7216x over previous
//
#include <hip/hip_runtime.h>
#include <hip/hip_bf16.h>
#include <stdint.h>

#define BATCH   65536
#define UNITS   256
#define NCH     16                     // BK=32
#define ROWP    68                     // shorts per column in gate buffer
#define GSZ     (64 * ROWP)            // 4352 shorts per gate
#define SMEM_BYTES 40960               // A dbuf 2*4KB + B dbuf 2*16KB; G (34816) reuses

using f32x16 = __attribute__((ext_vector_type(16))) float;
using bf16x8 = __attribute__((ext_vector_type(8))) short;

__device__ __forceinline__ short f2bf(float f) {
  union { float f; unsigned u; } v; v.f = f;
  unsigned r = v.u + 0x7FFFu + ((v.u >> 16) & 1u);   // RNE (prepass only)
  return (short)(r >> 16);
}
__device__ __forceinline__ float bf2f(short s) {
  union { float f; unsigned u; } v; v.u = ((unsigned)(unsigned short)s) << 16;
  return v.f;
}
__device__ __forceinline__ unsigned pk2(float a, float b) {   // v_cvt_pk_bf16_f32
  union { __hip_bfloat162 h; unsigned u; } cv;
  cv.h = __float22bfloat162_rn(make_float2(a, b));
  return cv.u;
}
__device__ __forceinline__ bf16x8 cvt8(float4 a, float4 b) {
  union { unsigned u[4]; bf16x8 v; } r;
  r.u[0] = pk2(a.x, a.y); r.u[1] = pk2(a.z, a.w);
  r.u[2] = pk2(b.x, b.y); r.u[3] = pk2(b.z, b.w);
  return r.v;
}
#define LOG2E 1.4426950408889634f
__device__ __forceinline__ float fast_sigmoid(float x) {
  return __builtin_amdgcn_rcpf(1.f + __builtin_amdgcn_exp2f(x * -LOG2E));
}
__device__ __forceinline__ float fast_tanh(float x) {
  return 2.f * __builtin_amdgcn_rcpf(1.f + __builtin_amdgcn_exp2f(x * (-2.f * LOG2E))) - 1.f;
}

#define BAR() do { asm volatile("s_waitcnt lgkmcnt(0)" ::: "memory"); \
                   __builtin_amdgcn_s_barrier(); } while (0)
#define WAITV(n) asm volatile("s_waitcnt vmcnt(" #n ")" ::: "memory")

__device__ __forceinline__ void gload_lds16(const void* gsrc, void* ldst) {
  __builtin_amdgcn_global_load_lds(
      (const __attribute__((address_space(1))) void*)gsrc,
      (__attribute__((address_space(3))) void*)ldst,
      16, 0, 0);
}

// ---- prepass: W_g fp32 [512][256] -> Wt bf16 tiled [g][nb][kg 64][n 64][k8]
// (linear per (g,nb): chunk c of BK=32 = bytes [c*4096, (c+1)*4096) — exact LDS image)
__global__ void cvt_weights(const float* __restrict__ Wf, const float* __restrict__ Wi,
                            const float* __restrict__ Wc, const float* __restrict__ Wo,
                            short* __restrict__ Wt) {
  int idx = blockIdx.x * 256 + threadIdx.x;
  int g   = idx >> 17;
  int k   = (idx >> 8) & 511;
  int col = idx & 255;
  const float* W = (g == 0) ? Wf : (g == 1) ? Wi : (g == 2) ? Wc : Wo;
  float val = W[k * 256 + col];
  int nb = col >> 6, n = col & 63;
  int kg = k >> 3, k8 = k & 7;
  int out = (((g * 4 + nb) * 64 + kg) * 64 + n) * 8 + k8;
  Wt[out] = f2bf(val);
}

// ---- fused LSTM cell: BK=32, A reg-staged->LDS dbuf, B staged to wave-private
// LDS via global_load_lds 2 chunks ahead, counted vmcnt (never drains prefetch).
// 4 waves (wave=gate), 4 blocks/CU (40KB LDS, <=128 regs).
__global__ __launch_bounds__(256, 4) void lstm_fused(
    const float* __restrict__ x, const float* __restrict__ hprev,
    const float* __restrict__ cprev, const short* __restrict__ Wt,
    const float* __restrict__ bfp, const float* __restrict__ bip,
    const float* __restrict__ bcp, const float* __restrict__ bop,
    float* __restrict__ hout, float* __restrict__ cout)
{
  extern __shared__ __align__(16) char smem[];
  const int tid  = threadIdx.x;
  const int g    = tid >> 6;           // wave = gate
  const int lane = tid & 63;
  const int la   = lane & 31;
  const int hh   = lane >> 5;

  int bid = blockIdx.x;
  int wg  = (bid & 7) * 512 + (bid >> 3);      // XCD-bijective swizzle
  const int m0 = (wg >> 2) * 64;
  const int nb = wg & 3;
  const int n0 = nb * 64;

  const short* WtG = Wt + ((size_t)(g * 4 + nb)) * 32768;   // 64KB bf16 per (g,nb)

  f32x16 acc[2][2] = {};
  float4 vA[2][2];

  const int arow  = tid >> 2;          // 0..63
  const int q     = tid & 3;           // kg within chunk
  const int slotW = arow ^ (q << 2);   // XOR swizzle (bits 2-3)

  char* Abase = smem;                  // [2][4096]
  char* Bbase = smem + 8192;           // [2][16384], + g*4096 wave-private

  auto ldA = [&](int c) {              // -> vA[c&1]
    const float* base = (c < 8) ? x : hprev;
    const float* rowp = base + (size_t)(m0 + arow) * 256 + (c & 7) * 32 + q * 8;
    vA[c & 1][0] = *(const float4*)(rowp);
    vA[c & 1][1] = *(const float4*)(rowp + 4);
  };
  auto wrA = [&](int c) {
    char* Ab = Abase + (c & 1) * 4096;
    *(bf16x8*)(Ab + q * 1024 + slotW * 16) = cvt8(vA[c & 1][0], vA[c & 1][1]);
  };
  auto stageB = [&](int c) {           // linear 4KB copy, wave-uniform dest
    char* ldst = Bbase + (c & 1) * 16384 + g * 4096;
    const short* gs = WtG + c * 2048 + lane * 8;
#pragma unroll
    for (int i = 0; i < 4; ++i)
      gload_lds16(gs + i * 512, ldst + i * 1024);
  };
  auto compute = [&](int c) {
    const char* Ab = Abase + (c & 1) * 4096;
    const char* Bl = Bbase + (c & 1) * 16384 + g * 4096;
#pragma unroll
    for (int ks = 0; ks < 2; ++ks) {
      const int kg = 2 * ks + hh;
      const int ao = kg * 1024 + ((la ^ (kg << 2)) * 16);
      bf16x8 a0 = *(const bf16x8*)(Ab + ao);
      bf16x8 a1 = *(const bf16x8*)(Ab + ao + 512);       // rows +32
      bf16x8 b0 = *(const bf16x8*)(Bl + kg * 1024 + la * 16);
      bf16x8 b1 = *(const bf16x8*)(Bl + kg * 1024 + la * 16 + 512);
      acc[0][0] = __builtin_amdgcn_mfma_f32_32x32x16_bf16(a0, b0, acc[0][0], 0, 0, 0);
      acc[0][1] = __builtin_amdgcn_mfma_f32_32x32x16_bf16(a0, b1, acc[0][1], 0, 0, 0);
      acc[1][0] = __builtin_amdgcn_mfma_f32_32x32x16_bf16(a1, b0, acc[1][0], 0, 0, 0);
      acc[1][1] = __builtin_amdgcn_mfma_f32_32x32x16_bf16(a1, b1, acc[1][1], 0, 0, 0);
    }
  };

  // ---- prologue: FIFO = A0,B0,A1,B1 ----
  ldA(0); stageB(0); ldA(1); stageB(1);
  wrA(0);                              // auto-vmcnt waits A(0) only (10 younger)

  // ---- K loop: one barrier/chunk, vmcnt never drained below prefetch depth ----
#pragma unroll
  for (int c = 0; c < NCH; ++c) {
    if (c + 2 < NCH) ldA(c + 2);       // HBM A prefetch (regs)
    if (c < NCH - 2)      WAITV(8);    // B(c) LDS-complete; 8 younger in flight
    else if (c == NCH - 2) WAITV(6);
    else                   WAITV(0);
    BAR();                             // A(c) visible; reads(c-1) retired
    if (c + 1 < NCH) wrA(c + 1);       // slot (c+1)&1 — disjoint from reads(c)
    compute(c);                        // MFMA lgkm-waits retire B(c) reads
    __builtin_amdgcn_sched_barrier(0); // don't hoist next stage above B reads
    if (c + 2 < NCH) stageB(c + 2);    // overwrites slot c&1 (wave-private, safe)
  }

  // ---- epilogue ----
  const int ccol = tid & 63;
  const int rg   = tid >> 6;
  const size_t gbase = (size_t)(m0 + rg * 16) * 256 + n0 + ccol;
  float cp[16];
#pragma unroll
  for (int j = 0; j < 16; ++j) cp[j] = cprev[gbase + (size_t)j * 256];

  const float* bptr = (g == 0) ? bfp : (g == 1) ? bip : (g == 2) ? bcp : bop;
  const float bias0 = bptr[n0 + la];
  const float bias1 = bptr[n0 + 32 + la];
  BAR();                               // all LDS traffic done; reuse as G
  short* G = (short*)smem;
#pragma unroll
  for (int mi = 0; mi < 2; ++mi)
#pragma unroll
    for (int ni = 0; ni < 2; ++ni) {
      const float bias = ni ? bias1 : bias0;
      const int   col  = la + ni * 32;
#pragma unroll
      for (int rq = 0; rq < 4; ++rq) {
        const int row0 = rq * 8 + 4 * hh + mi * 32;
        float t[4];
#pragma unroll
        for (int e = 0; e < 4; ++e) {
          float vv = acc[mi][ni][rq * 4 + e] + bias;
          t[e] = (g == 2) ? fast_tanh(vv) : fast_sigmoid(vv);
        }
        uint2 u; u.x = pk2(t[0], t[1]); u.y = pk2(t[2], t[3]);
        *(uint2*)(G + g * GSZ + col * ROWP + row0) = u;
      }
    }
  BAR();

  // ---- combine + store ----
  {
    const short* Gp = G + ccol * ROWP + rg * 16;
    bf16x8 gf[4][2];
#pragma unroll
    for (int gg = 0; gg < 4; ++gg) {
      gf[gg][0] = *(const bf16x8*)(Gp + gg * GSZ);
      gf[gg][1] = *(const bf16x8*)(Gp + gg * GSZ + 8);
    }
#pragma unroll
    for (int j = 0; j < 16; ++j) {
      float fg = bf2f(gf[0][j >> 3][j & 7]);
      float ig = bf2f(gf[1][j >> 3][j & 7]);
      float cg = bf2f(gf[2][j >> 3][j & 7]);
      float og = bf2f(gf[3][j >> 3][j & 7]);
      float cnew = fg * cp[j] + ig * cg;
      float hnew = og * fast_tanh(cnew);
      hout[gbase + (size_t)j * 256] = hnew;
      cout[gbase + (size_t)j * 256] = cnew;
    }
  }
}

extern "C" void kernel_launch(void* const* d_in, const int* in_sizes, int n_in,
                              void* d_out, int out_size, void* d_ws, size_t ws_size,
                              hipStream_t stream) {
  const float* x     = (const float*)d_in[0];
  const float* hprev = (const float*)d_in[1];
  const float* cprev = (const float*)d_in[2];
  const float* Wf    = (const float*)d_in[3];
  const float* Wi    = (const float*)d_in[4];
  const float* Wc    = (const float*)d_in[5];
  const float* Wo    = (const float*)d_in[6];
  const float* bfp   = (const float*)d_in[7];
  const float* bip   = (const float*)d_in[8];
  const float* bcp   = (const float*)d_in[9];
  const float* bop   = (const float*)d_in[10];
  float* out = (float*)d_out;
  short* Wt  = (short*)d_ws;     // 1 MB scratch

  cvt_weights<<<2048, 256, 0, stream>>>(Wf, Wi, Wc, Wo, Wt);

  lstm_fused<<<dim3(4096), dim3(256), SMEM_BYTES, stream>>>(
      x, hprev, cprev, Wt, bfp, bip, bcp, bop,
      out, out + (size_t)BATCH * UNITS);
}